// Round 5
// baseline (569.596 us; speedup 1.0000x reference)
//
#include <hip/hip_runtime.h>
#include <hip/hip_bf16.h>
#include <math.h>

typedef __bf16 bf16;
typedef bf16 bf16x8 __attribute__((ext_vector_type(8)));
typedef bf16 bf16x4 __attribute__((ext_vector_type(4)));
typedef float f32x4 __attribute__((ext_vector_type(4)));
typedef float f32x16 __attribute__((ext_vector_type(16)));

#define MFMA16(a, b, c) __builtin_amdgcn_mfma_f32_16x16x32_bf16(a, b, c, 0, 0, 0)
#define MFMA32(a, b, c) __builtin_amdgcn_mfma_f32_32x32x16_bf16(a, b, c, 0, 0, 0)
#define LOG2E 1.4426950408889634f
#define NEG_SHIFT -40.0f  // fixed softmax shift (base-2); cancels in O/l

__device__ __forceinline__ void glds16(const bf16* g, bf16* l) {
  // async global->LDS, 16B/lane; LDS dest = wave-uniform base + lane*16
  __builtin_amdgcn_global_load_lds(
      (const __attribute__((address_space(1))) void*)g,
      (__attribute__((address_space(3))) void*)l, 16, 0, 0);
}

__device__ inline unsigned pkbf(float a, float b) {
  union { bf16 h; unsigned short u; } ca, cb;
  ca.h = (bf16)a;
  cb.h = (bf16)b;
  return (unsigned)ca.u | ((unsigned)cb.u << 16);
}

// T5 bucket bias at window index x (= 2047 + rel), raw (unscaled).
__device__ inline float t5bias(const float* __restrict__ table, int h, int x) {
  if (x > 4094) return 0.f;  // pad slot
  int rel = x - 2047;
  int bucket = (rel > 0) ? 16 : 0;
  int ar = rel < 0 ? -rel : rel;
  int v;
  if (ar < 8) {
    v = ar;
  } else {
    double tt = log((double)ar / 8.0) / log(16.0) * 8.0;
    int lg = 8 + (int)tt;
    v = lg < 15 ? lg : 15;
  }
  return table[(bucket + v) * 8 + h];
}

// ---------------------------------------------------------------------------
// prep: [0,4096) rms+ln -> normed bf16 | [4096,4224) raw lut + remain |
//       [4224,5248) wt transpose | [5248,5376) lutq float4-replicated bias
// ---------------------------------------------------------------------------
__global__ __launch_bounds__(256) void prep_kernel(
    const float* __restrict__ hidden, const float* __restrict__ ln_w,
    const float* __restrict__ wq, const float* __restrict__ wk,
    const float* __restrict__ wv, const float* __restrict__ wo,
    const float* __restrict__ table, bf16* __restrict__ normed,
    float* __restrict__ lut, float4* __restrict__ lutq,
    float* __restrict__ out_remain, bf16* __restrict__ wt_qkv,
    bf16* __restrict__ wt_o) {
  __shared__ float tile[32][33];
  int bid = blockIdx.x;
  int t = threadIdx.x;
  if (bid < 4096) {
    int row = bid * 4 + (t >> 6);
    int lane = t & 63;
    const float4* xr = (const float4*)(hidden + (size_t)row * 512);
    float4 a = xr[lane];
    float4 b = xr[lane + 64];
    float s = a.x * a.x + a.y * a.y + a.z * a.z + a.w * a.w +
              b.x * b.x + b.y * b.y + b.z * b.z + b.w * b.w;
#pragma unroll
    for (int off = 32; off > 0; off >>= 1) s += __shfl_down(s, off, 64);
    float tot = __shfl(s, 0, 64);
    float rscale = rsqrtf(tot * (1.0f / 512.0f) + 1e-6f);
    float4 w0 = *(const float4*)(ln_w + 4 * lane);
    float4 w1 = *(const float4*)(ln_w + 256 + 4 * lane);
    bf16x4 o0, o1;
    o0[0] = (bf16)(a.x * rscale * w0.x);
    o0[1] = (bf16)(a.y * rscale * w0.y);
    o0[2] = (bf16)(a.z * rscale * w0.z);
    o0[3] = (bf16)(a.w * rscale * w0.w);
    o1[0] = (bf16)(b.x * rscale * w1.x);
    o1[1] = (bf16)(b.y * rscale * w1.y);
    o1[2] = (bf16)(b.z * rscale * w1.z);
    o1[3] = (bf16)(b.w * rscale * w1.w);
    *(bf16x4*)(normed + (size_t)row * 512 + 4 * lane) = o0;
    *(bf16x4*)(normed + (size_t)row * 512 + 256 + 4 * lane) = o1;
  } else if (bid < 4224) {
    int i = (bid - 4096) * 256 + t;  // 8 * 4096
    int h = i >> 12;
    int d = i & 4095;
    lut[(size_t)h * 4096 + d] = t5bias(table, h, d);
    if (i < 8) out_remain[i] = (float)i;
  } else if (bid < 5248) {
    int bid2 = bid - 4224;
    int mat = bid2 >> 8;
    int rem = bid2 & 255;
    int e0 = (rem & 15) * 32;
    int k0 = (rem >> 4) * 32;
    int tx = t & 31, ty = t >> 5;
    const float* W = (mat == 0) ? wq : (mat == 1) ? wk : (mat == 2) ? wv : wo;
#pragma unroll
    for (int j = 0; j < 32; j += 8)
      tile[ty + j][tx] = W[(size_t)(k0 + ty + j) * 512 + e0 + tx];
    __syncthreads();
    bf16* dst = (mat < 3) ? (wt_qkv + (size_t)mat * 512 * 512) : wt_o;
#pragma unroll
    for (int j = 0; j < 32; j += 8)
      dst[(size_t)(e0 + ty + j) * 512 + k0 + tx] = (bf16)tile[tx][ty + j];
  } else {
    int i = (bid - 5248) * 256 + t;  // 8 * 4096
    int h = i >> 12;
    int d = i & 4095;
    float4 o;
    o.x = t5bias(table, h, d);
    o.y = t5bias(table, h, d + 1);
    o.z = t5bias(table, h, d + 2);
    o.w = t5bias(table, h, d + 3);
    lutq[(size_t)h * 4096 + d] = o;
  }
}

// ---------------------------------------------------------------------------
// qkv GEMM: pure bf16, global_load_lds staging ([128][32] tiles, m97-style).
// Q/K -> [n][h][s][d] via LDS-staged coalesced stores; V stored directly
// transposed to vt[n][h][d][s] (8B stores; acc r-index = 4 consecutive s).
// ---------------------------------------------------------------------------
__global__ __launch_bounds__(256) void qkv_gemm(
    const bf16* __restrict__ normed, const bf16* __restrict__ wt,
    bf16* __restrict__ qb, bf16* __restrict__ kb, bf16* __restrict__ vtb) {
  __shared__ __align__(16) char smem[19456];
  bf16* As = (bf16*)smem;           // [128][32]
  bf16* Bs = (bf16*)(smem + 8192);  // [128][32]
  int t = threadIdx.x;
  int wave = t >> 6, lane = t & 63;
  int quad = lane >> 4, lc = lane & 15;
  int wm = wave >> 1, wn = wave & 1;
  int m0 = blockIdx.x * 128, n0 = blockIdx.y * 128;

  f32x4 acc[4][4];
#pragma unroll
  for (int i = 0; i < 4; i++)
#pragma unroll
    for (int j = 0; j < 4; j++) acc[i][j] = (f32x4){0.f, 0.f, 0.f, 0.f};

  int rw = lane >> 2;        // 0..15
  int c8 = (lane & 3) * 8;   // element col within 32
  const bf16* gA = normed + (size_t)(m0 + wave * 32 + rw) * 512 + c8;
  const bf16* gB = wt + (size_t)(n0 + wave * 32 + rw) * 512 + c8;
  bf16* lA = As + wave * 1024;  // wave-uniform LDS base
  bf16* lB = Bs + wave * 1024;

  for (int kt = 0; kt < 16; ++kt) {
    int k0 = kt * 32;
    __syncthreads();  // prev iter's frag reads done before overwrite
    glds16(gA + k0, lA);
    glds16(gA + 16 * 512 + k0, lA + 512);
    glds16(gB + k0, lB);
    glds16(gB + 16 * 512 + k0, lB + 512);
    __syncthreads();  // vmcnt(0) drain + barrier
    bf16x8 af[4], bfr[4];
#pragma unroll
    for (int i = 0; i < 4; i++)
      af[i] = *(const bf16x8*)&As[(wm * 64 + i * 16 + lc) * 32 + quad * 8];
#pragma unroll
    for (int j = 0; j < 4; j++)
      bfr[j] = *(const bf16x8*)&Bs[(wn * 64 + j * 16 + lc) * 32 + quad * 8];
#pragma unroll
    for (int i = 0; i < 4; i++)
#pragma unroll
      for (int j = 0; j < 4; j++)
        acc[i][j] = MFMA16(af[i], bfr[j], acc[i][j]);
  }

  __syncthreads();  // all frag reads done before LDS reuse / epilogue
  int mat = n0 >> 9;
  int e_base = (n0 & 511) + wn * 64;
  int hh = e_base >> 6;
  int grow0 = m0 + wm * 64;
  int nbi = grow0 >> 11, sbase = grow0 & 2047;

  if (mat == 2) {
    // V: direct transposed stores vt[bh][d][s] (8B per store)
    bf16* dv = vtb + ((size_t)(nbi * 8 + hh) * 64) * 2048;
#pragma unroll
    for (int i = 0; i < 4; i++) {
      int s = sbase + i * 16 + quad * 4;
#pragma unroll
      for (int j = 0; j < 4; j++) {
        int d = j * 16 + lc;
        bf16x4 o4;
#pragma unroll
        for (int r = 0; r < 4; r++) o4[r] = (bf16)acc[i][j][r];
        *(bf16x4*)(dv + (size_t)d * 2048 + s) = o4;
      }
    }
  } else {
    bf16* dst0 = (mat == 0) ? qb : kb;
    bf16* dst = dst0 + (((size_t)nbi * 8 + hh) * 2048 + sbase) * 64;
    bf16* Cw = (bf16*)smem + wave * 2432;  // 32x76 per wave
#pragma unroll
    for (int p = 0; p < 2; ++p) {
#pragma unroll
      for (int i2 = 0; i2 < 2; ++i2) {
#pragma unroll
        for (int j = 0; j < 4; ++j)
#pragma unroll
          for (int r = 0; r < 4; ++r)
            Cw[(i2 * 16 + quad * 4 + r) * 76 + j * 16 + lc] =
                (bf16)acc[2 * p + i2][j][r];
      }
      // wave-local write->read; compiler inserts lgkmcnt wait
#pragma unroll
      for (int c = 0; c < 4; ++c) {
        bf16x8 vch =
            *(const bf16x8*)&Cw[(c * 8 + (lane >> 3)) * 76 + (lane & 7) * 8];
        *(bf16x8*)(dst + (size_t)(p * 32 + c * 8 + (lane >> 3)) * 64 +
                   (lane & 7) * 8) = vch;
      }
    }
  }
}

// ---------------------------------------------------------------------------
// attn + bias: blocks [0,512) = flash attention, q-tile 256 (wave owns 64 q
// as 2x32 sets -> K/V staging + barriers amortized 2x); blocks [512,33280) =
// position_bias materialization (overlaps attn).
// ---------------------------------------------------------------------------
__global__ __launch_bounds__(256, 3) void attn_bias_kernel(
    const bf16* __restrict__ qg, const bf16* __restrict__ kg,
    const bf16* __restrict__ vtg, const float4* __restrict__ lutq,
    const float* __restrict__ lutg, bf16* __restrict__ ctx,
    float* __restrict__ bias_out) {
  __shared__ bf16 Ks[64][72];  // 9216 B
  __shared__ bf16 Vs[64][72];  // 9216 B
  int t = threadIdx.x;

  if (blockIdx.x >= 512) {  // ---- bias path ----
    size_t i = (((size_t)blockIdx.x - 512) * 256 + t) * 4;
    int h = (int)(i >> 22);
    int q = (int)((i >> 11) & 2047);
    int k = (int)(i & 2047);
    const float* lh = lutg + (size_t)h * 4096 + (2047 - q);
    float4 v = {lh[k], lh[k + 1], lh[k + 2], lh[k + 3]};
    *(float4*)(bias_out + i) = v;
    return;
  }

  // ---- attention path ----
  int id = blockIdx.x;
  int xcd = id & 7, slot = id >> 3;  // each XCD owns 8 whole bh
  int bh = xcd * 8 + (slot >> 3);
  int qt = slot & 7;
  int n = bh >> 3, h = bh & 7;
  int q0 = qt * 256;

  int wave = t >> 6, lane = t & 63;
  int l31 = lane & 31, hi = lane >> 5;
  int qA = q0 + wave * 64 + l31;  // qs=0 column
  const float4* bq = lutq + (size_t)h * 4096;
  int cbA = 2047 + 4 * hi - qA;   // qs=0 window base; qs=1 is -32

  const bf16* qp = qg + ((size_t)bh * 2048 + qA) * 64;
  bf16x8 Qf[2][4];
#pragma unroll
  for (int c = 0; c < 4; c++) {
    Qf[0][c] = *(const bf16x8*)(qp + c * 16 + hi * 8);
    Qf[1][c] = *(const bf16x8*)(qp + 32 * 64 + c * 16 + hi * 8);
  }

  f32x16 O[2][2];
#pragma unroll
  for (int a = 0; a < 2; a++)
#pragma unroll
    for (int b = 0; b < 2; b++)
#pragma unroll
      for (int e = 0; e < 16; e++) O[a][b][e] = 0.f;
  float ls0[2] = {0.f, 0.f}, ls1[2] = {0.f, 0.f};

  int srow = t >> 2, scol = (t & 3) * 16;
  const bf16* kp = kg + (size_t)bh * 2048 * 64;
  const bf16* vp = vtg + (size_t)bh * 64 * 2048;

  // prefetch tile 0
  bf16x8 kv0 = *(const bf16x8*)(kp + (size_t)srow * 64 + scol);
  bf16x8 kv1 = *(const bf16x8*)(kp + (size_t)srow * 64 + scol + 8);
  bf16x8 vv0 = *(const bf16x8*)(vp + (size_t)srow * 2048 + scol);
  bf16x8 vv1 = *(const bf16x8*)(vp + (size_t)srow * 2048 + scol + 8);

  for (int kt = 0; kt < 32; ++kt) {
    int kr0 = kt * 64;
    __syncthreads();
    *(bf16x8*)&Ks[srow][scol] = kv0;
    *(bf16x8*)&Ks[srow][scol + 8] = kv1;
    *(bf16x8*)&Vs[srow][scol] = vv0;
    *(bf16x8*)&Vs[srow][scol + 8] = vv1;
    __syncthreads();
    if (kt + 1 < 32) {  // prefetch next K/V tile during compute
      int kn = kr0 + 64;
      kv0 = *(const bf16x8*)(kp + (size_t)(kn + srow) * 64 + scol);
      kv1 = *(const bf16x8*)(kp + (size_t)(kn + srow) * 64 + scol + 8);
      vv0 = *(const bf16x8*)(vp + (size_t)srow * 2048 + kn + scol);
      vv1 = *(const bf16x8*)(vp + (size_t)srow * 2048 + kn + scol + 8);
    }

#pragma unroll
    for (int qs = 0; qs < 2; ++qs) {
      int cb = cbA - 32 * qs + kr0;
#pragma unroll
      for (int mi = 0; mi < 2; mi++) {
        // bias -> MFMA C-operand (VMEM, L1/L2-resident)
        f32x16 st;
#pragma unroll
        for (int g = 0; g < 4; g++) {
          float4 b4 = bq[cb + mi * 32 + 8 * g];
          st[4 * g + 0] = b4.x;
          st[4 * g + 1] = b4.y;
          st[4 * g + 2] = b4.z;
          st[4 * g + 3] = b4.w;
        }
#pragma unroll
        for (int c = 0; c < 4; c++) {
          bf16x8 kf = *(const bf16x8*)&Ks[mi * 32 + l31][c * 16 + hi * 8];
          st = MFMA32(kf, Qf[qs][c], st);
        }
        unsigned D[8], X[8];
#pragma unroll
        for (int g = 0; g < 4; g++) {
#pragma unroll
          for (int e = 0; e < 4; e++) {
            float p = __builtin_amdgcn_exp2f(fmaf(st[4 * g + e], LOG2E, NEG_SHIFT));
            st[4 * g + e] = p;
            if (e & 1) ls1[qs] += p; else ls0[qs] += p;
          }
          D[2 * g] = pkbf(st[4 * g + 0], st[4 * g + 1]);
          D[2 * g + 1] = pkbf(st[4 * g + 2], st[4 * g + 3]);
        }
#pragma unroll
        for (int tt = 0; tt < 8; tt++) X[tt] = __shfl_xor(D[tt], 32, 64);

#pragma unroll
        for (int kk = 0; kk < 2; kk++) {
          int kc = 2 * mi + kk;
          int b = 4 * kk;
          unsigned f0 = hi ? X[b + 2] : D[b + 0];
          unsigned f1 = hi ? X[b + 3] : D[b + 1];
          unsigned f2 = hi ? D[b + 2] : X[b + 0];
          unsigned f3 = hi ? D[b + 3] : X[b + 1];
          union { uint4 u; bf16x8 v; } cv;
          cv.u = make_uint4(f0, f1, f2, f3);
          bf16x8 pf = cv.v;
#pragma unroll
          for (int md = 0; md < 2; md++) {
            bf16x8 vf = *(const bf16x8*)&Vs[md * 32 + l31][kc * 16 + hi * 8];
            O[qs][md] = MFMA32(vf, pf, O[qs][md]);
          }
        }
      }
    }
  }

#pragma unroll
  for (int qs = 0; qs < 2; ++qs) {
    float l_run = ls0[qs] + ls1[qs];
    l_run += __shfl_xor(l_run, 32, 64);
    float inv = 1.0f / l_run;
    bf16* cp = ctx + ((size_t)n * 2048 + qA + 32 * qs) * 512 + h * 64;
#pragma unroll
    for (int md = 0; md < 2; md++)
#pragma unroll
      for (int g = 0; g < 4; g++) {
        bf16x4 o4;
#pragma unroll
        for (int e = 0; e < 4; e++) o4[e] = (bf16)(O[qs][md][4 * g + e] * inv);
        *(bf16x4*)(cp + md * 32 + 8 * g + hi * 4) = o4;
      }
  }
}

// ---------------------------------------------------------------------------
// oproj: out = ctx @ wo + hidden (residual), fp32 out. glds staging.
// ---------------------------------------------------------------------------
__global__ __launch_bounds__(256) void oproj_gemm(
    const bf16* __restrict__ ctx, const bf16* __restrict__ wt_o,
    const float* __restrict__ hidden, float* __restrict__ out) {
  __shared__ __align__(16) char smem[16384];
  bf16* As = (bf16*)smem;
  bf16* Bs = (bf16*)(smem + 8192);
  int t = threadIdx.x;
  int wave = t >> 6, lane = t & 63;
  int quad = lane >> 4, lc = lane & 15;
  int wm = wave >> 1, wn = wave & 1;
  int m0 = blockIdx.x * 128, n0 = blockIdx.y * 128;

  f32x4 acc[4][4];
#pragma unroll
  for (int i = 0; i < 4; i++)
#pragma unroll
    for (int j = 0; j < 4; j++) acc[i][j] = (f32x4){0.f, 0.f, 0.f, 0.f};

  int rw = lane >> 2;
  int c8 = (lane & 3) * 8;
  const bf16* gA = ctx + (size_t)(m0 + wave * 32 + rw) * 512 + c8;
  const bf16* gB = wt_o + (size_t)(n0 + wave * 32 + rw) * 512 + c8;
  bf16* lA = As + wave * 1024;
  bf16* lB = Bs + wave * 1024;

  for (int kt = 0; kt < 16; ++kt) {
    int k0 = kt * 32;
    __syncthreads();
    glds16(gA + k0, lA);
    glds16(gA + 16 * 512 + k0, lA + 512);
    glds16(gB + k0, lB);
    glds16(gB + 16 * 512 + k0, lB + 512);
    __syncthreads();
    bf16x8 af[4], bfr[4];
#pragma unroll
    for (int i = 0; i < 4; i++)
      af[i] = *(const bf16x8*)&As[(wm * 64 + i * 16 + lc) * 32 + quad * 8];
#pragma unroll
    for (int j = 0; j < 4; j++)
      bfr[j] = *(const bf16x8*)&Bs[(wn * 64 + j * 16 + lc) * 32 + quad * 8];
#pragma unroll
    for (int i = 0; i < 4; i++)
#pragma unroll
      for (int j = 0; j < 4; j++)
        acc[i][j] = MFMA16(af[i], bfr[j], acc[i][j]);
  }

#pragma unroll
  for (int i = 0; i < 4; i++) {
#pragma unroll
    for (int j = 0; j < 4; j++) {
#pragma unroll
      for (int r = 0; r < 4; r++) {
        int grow = m0 + wm * 64 + i * 16 + quad * 4 + r;
        int gcol = n0 + wn * 64 + j * 16 + lc;
        size_t idx = (size_t)grow * 512 + gcol;
        out[idx] = acc[i][j][r] + hidden[idx];
      }
    }
  }
}

// ---------------------------------------------------------------------------
extern "C" void kernel_launch(void* const* d_in, const int* in_sizes, int n_in,
                              void* d_out, int out_size, void* d_ws, size_t ws_size,
                              hipStream_t stream) {
  const float* hidden = (const float*)d_in[0];
  const float* ln_w = (const float*)d_in[1];
  const float* wq = (const float*)d_in[2];
  const float* wk = (const float*)d_in[3];
  const float* wv = (const float*)d_in[4];
  const float* wo = (const float*)d_in[5];
  const float* table = (const float*)d_in[6];

  float* out_hidden = (float*)d_out;                       // 8*2048*512
  float* out_bias = out_hidden + (size_t)8 * 2048 * 512;   // 8*2048*2048
  float* out_remain = out_bias + (size_t)8 * 2048 * 2048;  // 8

  char* ws = (char*)d_ws;
  bf16* normed = (bf16*)(ws + 0);            // 16 MiB (reused as ctx later)
  float* lut = (float*)(ws + 16777216);      // 128 KiB
  float4* lutq = (float4*)(ws + 16908288);   // 512 KiB
  bf16* wt_qkv = (bf16*)(ws + 17432576);     // 1.5 MiB
  bf16* wt_o = (bf16*)(ws + 19005440);       // 0.5 MiB
  bf16* qb = (bf16*)(ws + 19529728);         // 16 MiB each
  bf16* kb = qb + (size_t)8 * 8 * 2048 * 64;
  bf16* vtb = kb + (size_t)8 * 8 * 2048 * 64;
  bf16* ctx = normed;  // alias: normed consumed by qkv before attn writes ctx

  prep_kernel<<<dim3(5376), dim3(256), 0, stream>>>(
      hidden, ln_w, wq, wk, wv, wo, table, normed, lut, lutq, out_remain,
      wt_qkv, wt_o);
  qkv_gemm<<<dim3(128, 12), dim3(256), 0, stream>>>(normed, wt_qkv, qb, kb, vtb);
  attn_bias_kernel<<<dim3(512 + 32768), dim3(256), 0, stream>>>(
      qb, kb, vtb, lutq, lut, ctx, out_bias);
  oproj_gemm<<<dim3(128, 4), dim3(256), 0, stream>>>(ctx, wt_o, hidden, out_hidden);
}

// Round 6
// 358.443 us; speedup vs baseline: 1.5891x; 1.5891x over previous
//
#include <hip/hip_runtime.h>
#include <hip/hip_bf16.h>
#include <math.h>

typedef __bf16 bf16;
typedef bf16 bf16x8 __attribute__((ext_vector_type(8)));
typedef bf16 bf16x4 __attribute__((ext_vector_type(4)));
typedef float f32x4 __attribute__((ext_vector_type(4)));
typedef float f32x16 __attribute__((ext_vector_type(16)));

#define MFMA16(a, b, c) __builtin_amdgcn_mfma_f32_16x16x32_bf16(a, b, c, 0, 0, 0)
#define MFMA32(a, b, c) __builtin_amdgcn_mfma_f32_32x32x16_bf16(a, b, c, 0, 0, 0)
#define LOG2E 1.4426950408889634f
#define NEG_SHIFT -40.0f  // fixed softmax shift (base-2); cancels in O/l

__device__ __forceinline__ void glds16(const bf16* g, bf16* l) {
  // async global->LDS, 16B/lane; LDS dest = wave-uniform base + lane*16
  __builtin_amdgcn_global_load_lds(
      (const __attribute__((address_space(1))) void*)g,
      (__attribute__((address_space(3))) void*)l, 16, 0, 0);
}

__device__ inline unsigned pkbf(float a, float b) {
  union { bf16 h; unsigned short u; } ca, cb;
  ca.h = (bf16)a;
  cb.h = (bf16)b;
  return (unsigned)ca.u | ((unsigned)cb.u << 16);
}

// T5 bucket bias at window index x (= 2047 + rel), raw (unscaled).
__device__ inline float t5bias(const float* __restrict__ table, int h, int x) {
  if (x > 4094) return 0.f;  // pad slot
  int rel = x - 2047;
  int bucket = (rel > 0) ? 16 : 0;
  int ar = rel < 0 ? -rel : rel;
  int v;
  if (ar < 8) {
    v = ar;
  } else {
    double tt = log((double)ar / 8.0) / log(16.0) * 8.0;
    int lg = 8 + (int)tt;
    v = lg < 15 ? lg : 15;
  }
  return table[(bucket + v) * 8 + h];
}

// ---------------------------------------------------------------------------
// prep: [0,4096) rms+ln -> normed bf16 | [4096,4224) raw lut + remain |
//       [4224,5248) wt transpose | [5248,5376) lutq float4-replicated bias
// ---------------------------------------------------------------------------
__global__ __launch_bounds__(256) void prep_kernel(
    const float* __restrict__ hidden, const float* __restrict__ ln_w,
    const float* __restrict__ wq, const float* __restrict__ wk,
    const float* __restrict__ wv, const float* __restrict__ wo,
    const float* __restrict__ table, bf16* __restrict__ normed,
    float* __restrict__ lut, float4* __restrict__ lutq,
    float* __restrict__ out_remain, bf16* __restrict__ wt_qkv,
    bf16* __restrict__ wt_o) {
  __shared__ float tile[32][33];
  int bid = blockIdx.x;
  int t = threadIdx.x;
  if (bid < 4096) {
    int row = bid * 4 + (t >> 6);
    int lane = t & 63;
    const float4* xr = (const float4*)(hidden + (size_t)row * 512);
    float4 a = xr[lane];
    float4 b = xr[lane + 64];
    float s = a.x * a.x + a.y * a.y + a.z * a.z + a.w * a.w +
              b.x * b.x + b.y * b.y + b.z * b.z + b.w * b.w;
#pragma unroll
    for (int off = 32; off > 0; off >>= 1) s += __shfl_down(s, off, 64);
    float tot = __shfl(s, 0, 64);
    float rscale = rsqrtf(tot * (1.0f / 512.0f) + 1e-6f);
    float4 w0 = *(const float4*)(ln_w + 4 * lane);
    float4 w1 = *(const float4*)(ln_w + 256 + 4 * lane);
    bf16x4 o0, o1;
    o0[0] = (bf16)(a.x * rscale * w0.x);
    o0[1] = (bf16)(a.y * rscale * w0.y);
    o0[2] = (bf16)(a.z * rscale * w0.z);
    o0[3] = (bf16)(a.w * rscale * w0.w);
    o1[0] = (bf16)(b.x * rscale * w1.x);
    o1[1] = (bf16)(b.y * rscale * w1.y);
    o1[2] = (bf16)(b.z * rscale * w1.z);
    o1[3] = (bf16)(b.w * rscale * w1.w);
    *(bf16x4*)(normed + (size_t)row * 512 + 4 * lane) = o0;
    *(bf16x4*)(normed + (size_t)row * 512 + 256 + 4 * lane) = o1;
  } else if (bid < 4224) {
    int i = (bid - 4096) * 256 + t;  // 8 * 4096
    int h = i >> 12;
    int d = i & 4095;
    lut[(size_t)h * 4096 + d] = t5bias(table, h, d);
    if (i < 8) out_remain[i] = (float)i;
  } else if (bid < 5248) {
    int bid2 = bid - 4224;
    int mat = bid2 >> 8;
    int rem = bid2 & 255;
    int e0 = (rem & 15) * 32;
    int k0 = (rem >> 4) * 32;
    int tx = t & 31, ty = t >> 5;
    const float* W = (mat == 0) ? wq : (mat == 1) ? wk : (mat == 2) ? wv : wo;
#pragma unroll
    for (int j = 0; j < 32; j += 8)
      tile[ty + j][tx] = W[(size_t)(k0 + ty + j) * 512 + e0 + tx];
    __syncthreads();
    bf16* dst = (mat < 3) ? (wt_qkv + (size_t)mat * 512 * 512) : wt_o;
#pragma unroll
    for (int j = 0; j < 32; j += 8)
      dst[(size_t)(e0 + ty + j) * 512 + k0 + tx] = (bf16)tile[tx][ty + j];
  } else {
    int i = (bid - 5248) * 256 + t;  // 8 * 4096
    int h = i >> 12;
    int d = i & 4095;
    float4 o;
    o.x = t5bias(table, h, d);
    o.y = t5bias(table, h, d + 1);
    o.z = t5bias(table, h, d + 2);
    o.w = t5bias(table, h, d + 3);
    lutq[(size_t)h * 4096 + d] = o;
  }
}

// ---------------------------------------------------------------------------
// qkv GEMM: pure bf16, global_load_lds staging ([128][32] tiles, m97-style).
// Q/K -> [n][h][s][d] via LDS-staged coalesced stores; V stored directly
// transposed to vt[n][h][d][s] (8B stores; acc r-index = 4 consecutive s).
// ---------------------------------------------------------------------------
__global__ __launch_bounds__(256) void qkv_gemm(
    const bf16* __restrict__ normed, const bf16* __restrict__ wt,
    bf16* __restrict__ qb, bf16* __restrict__ kb, bf16* __restrict__ vtb) {
  __shared__ __align__(16) char smem[19456];
  bf16* As = (bf16*)smem;           // [128][32]
  bf16* Bs = (bf16*)(smem + 8192);  // [128][32]
  int t = threadIdx.x;
  int wave = t >> 6, lane = t & 63;
  int quad = lane >> 4, lc = lane & 15;
  int wm = wave >> 1, wn = wave & 1;
  int m0 = blockIdx.x * 128, n0 = blockIdx.y * 128;

  f32x4 acc[4][4];
#pragma unroll
  for (int i = 0; i < 4; i++)
#pragma unroll
    for (int j = 0; j < 4; j++) acc[i][j] = (f32x4){0.f, 0.f, 0.f, 0.f};

  int rw = lane >> 2;        // 0..15
  int c8 = (lane & 3) * 8;   // element col within 32
  const bf16* gA = normed + (size_t)(m0 + wave * 32 + rw) * 512 + c8;
  const bf16* gB = wt + (size_t)(n0 + wave * 32 + rw) * 512 + c8;
  bf16* lA = As + wave * 1024;  // wave-uniform LDS base
  bf16* lB = Bs + wave * 1024;

  for (int kt = 0; kt < 16; ++kt) {
    int k0 = kt * 32;
    __syncthreads();  // prev iter's frag reads done before overwrite
    glds16(gA + k0, lA);
    glds16(gA + 16 * 512 + k0, lA + 512);
    glds16(gB + k0, lB);
    glds16(gB + 16 * 512 + k0, lB + 512);
    __syncthreads();  // vmcnt(0) drain + barrier
    bf16x8 af[4], bfr[4];
#pragma unroll
    for (int i = 0; i < 4; i++)
      af[i] = *(const bf16x8*)&As[(wm * 64 + i * 16 + lc) * 32 + quad * 8];
#pragma unroll
    for (int j = 0; j < 4; j++)
      bfr[j] = *(const bf16x8*)&Bs[(wn * 64 + j * 16 + lc) * 32 + quad * 8];
#pragma unroll
    for (int i = 0; i < 4; i++)
#pragma unroll
      for (int j = 0; j < 4; j++)
        acc[i][j] = MFMA16(af[i], bfr[j], acc[i][j]);
  }

  __syncthreads();  // all frag reads done before LDS reuse / epilogue
  int mat = n0 >> 9;
  int e_base = (n0 & 511) + wn * 64;
  int hh = e_base >> 6;
  int grow0 = m0 + wm * 64;
  int nbi = grow0 >> 11, sbase = grow0 & 2047;

  if (mat == 2) {
    // V: direct transposed stores vt[bh][d][s] (8B per store)
    bf16* dv = vtb + ((size_t)(nbi * 8 + hh) * 64) * 2048;
#pragma unroll
    for (int i = 0; i < 4; i++) {
      int s = sbase + i * 16 + quad * 4;
#pragma unroll
      for (int j = 0; j < 4; j++) {
        int d = j * 16 + lc;
        bf16x4 o4;
#pragma unroll
        for (int r = 0; r < 4; r++) o4[r] = (bf16)acc[i][j][r];
        *(bf16x4*)(dv + (size_t)d * 2048 + s) = o4;
      }
    }
  } else {
    bf16* dst0 = (mat == 0) ? qb : kb;
    bf16* dst = dst0 + (((size_t)nbi * 8 + hh) * 2048 + sbase) * 64;
    bf16* Cw = (bf16*)smem + wave * 2432;  // 32x76 per wave
#pragma unroll
    for (int p = 0; p < 2; ++p) {
#pragma unroll
      for (int i2 = 0; i2 < 2; ++i2) {
#pragma unroll
        for (int j = 0; j < 4; ++j)
#pragma unroll
          for (int r = 0; r < 4; ++r)
            Cw[(i2 * 16 + quad * 4 + r) * 76 + j * 16 + lc] =
                (bf16)acc[2 * p + i2][j][r];
      }
      // wave-local write->read; compiler inserts lgkmcnt wait
#pragma unroll
      for (int c = 0; c < 4; ++c) {
        bf16x8 vch =
            *(const bf16x8*)&Cw[(c * 8 + (lane >> 3)) * 76 + (lane & 7) * 8];
        *(bf16x8*)(dst + (size_t)(p * 32 + c * 8 + (lane >> 3)) * 64 +
                   (lane & 7) * 8) = vch;
      }
    }
  }
}

// ---------------------------------------------------------------------------
// attn + bias: blocks [0,1024) = flash attention (round-4 proven config:
// q-tile 128, wave owns 32 q, 68 VGPR, no spill); blocks [1024,33792) =
// position_bias materialization (overlaps attn).
// ---------------------------------------------------------------------------
__global__ __launch_bounds__(256, 3) void attn_bias_kernel(
    const bf16* __restrict__ qg, const bf16* __restrict__ kg,
    const bf16* __restrict__ vtg, const float4* __restrict__ lutq,
    const float* __restrict__ lutg, bf16* __restrict__ ctx,
    float* __restrict__ bias_out) {
  __shared__ bf16 Ks[64][72];  // 9216 B
  __shared__ bf16 Vs[64][72];  // 9216 B
  int t = threadIdx.x;

  if (blockIdx.x >= 1024) {  // ---- bias path ----
    size_t i = (((size_t)blockIdx.x - 1024) * 256 + t) * 4;
    int h = (int)(i >> 22);
    int q = (int)((i >> 11) & 2047);
    int k = (int)(i & 2047);
    const float* lh = lutg + (size_t)h * 4096 + (2047 - q);
    float4 v = {lh[k], lh[k + 1], lh[k + 2], lh[k + 3]};
    *(float4*)(bias_out + i) = v;
    return;
  }

  // ---- attention path ----
  int id = blockIdx.x;
  int xcd = id & 7, slot = id >> 3;  // XCD-aware: each XCD owns 8 whole bh
  int bh = xcd * 8 + (slot >> 4);
  int qt = slot & 15;
  int n = bh >> 3, h = bh & 7;
  int q0 = qt * 128;

  int wave = t >> 6, lane = t & 63;
  int l31 = lane & 31, hi = lane >> 5;
  int q = q0 + wave * 32 + l31;

  const float4* bq = lutq + (size_t)h * 4096;
  int cbase = 2047 + 4 * hi - q;  // window index base (rel = k - q)

  // Q fragments: B[k=d][n=q], from global (L2-hot)
  const bf16* qp = qg + ((size_t)bh * 2048 + q) * 64;
  bf16x8 Qf[4];
#pragma unroll
  for (int c = 0; c < 4; c++) Qf[c] = *(const bf16x8*)(qp + c * 16 + hi * 8);

  f32x16 O[2];
#pragma unroll
  for (int i = 0; i < 2; i++)
#pragma unroll
    for (int e = 0; e < 16; e++) O[i][e] = 0.f;
  float lsum0 = 0.f, lsum1 = 0.f;

  int srow = t >> 2, scol = (t & 3) * 16;
  const bf16* kp = kg + (size_t)bh * 2048 * 64;
  const bf16* vp = vtg + (size_t)bh * 64 * 2048;

  // prefetch tile 0
  bf16x8 kv0 = *(const bf16x8*)(kp + (size_t)srow * 64 + scol);
  bf16x8 kv1 = *(const bf16x8*)(kp + (size_t)srow * 64 + scol + 8);
  bf16x8 vv0 = *(const bf16x8*)(vp + (size_t)srow * 2048 + scol);
  bf16x8 vv1 = *(const bf16x8*)(vp + (size_t)srow * 2048 + scol + 8);

  for (int kt = 0; kt < 32; ++kt) {
    int kr0 = kt * 64;
    __syncthreads();
    *(bf16x8*)&Ks[srow][scol] = kv0;
    *(bf16x8*)&Ks[srow][scol + 8] = kv1;
    *(bf16x8*)&Vs[srow][scol] = vv0;
    *(bf16x8*)&Vs[srow][scol + 8] = vv1;
    __syncthreads();

    // bias -> MFMA C-operand (VMEM; table is L1/L2-resident)
    f32x16 st[2];
#pragma unroll
    for (int mi = 0; mi < 2; mi++)
#pragma unroll
      for (int g = 0; g < 4; g++) {
        float4 b4 = bq[cbase + kr0 + mi * 32 + 8 * g];
        st[mi][4 * g + 0] = b4.x;
        st[mi][4 * g + 1] = b4.y;
        st[mi][4 * g + 2] = b4.z;
        st[mi][4 * g + 3] = b4.w;
      }

    if (kt + 1 < 32) {  // prefetch next K/V tile during compute
      int kn = kr0 + 64;
      kv0 = *(const bf16x8*)(kp + (size_t)(kn + srow) * 64 + scol);
      kv1 = *(const bf16x8*)(kp + (size_t)(kn + srow) * 64 + scol + 8);
      vv0 = *(const bf16x8*)(vp + (size_t)srow * 2048 + kn + scol);
      vv1 = *(const bf16x8*)(vp + (size_t)srow * 2048 + kn + scol + 8);
    }

    // per-mi pipeline: QK^T -> exp -> pack -> PV (caps transient VGPRs)
#pragma unroll
    for (int mi = 0; mi < 2; mi++) {
#pragma unroll
      for (int c = 0; c < 4; c++) {
        bf16x8 kf = *(const bf16x8*)&Ks[mi * 32 + l31][c * 16 + hi * 8];
        st[mi] = MFMA32(kf, Qf[c], st[mi]);
      }
      unsigned D[8], X[8];
#pragma unroll
      for (int g = 0; g < 4; g++) {
#pragma unroll
        for (int e = 0; e < 4; e++) {
          float p = __builtin_amdgcn_exp2f(fmaf(st[mi][4 * g + e], LOG2E, NEG_SHIFT));
          st[mi][4 * g + e] = p;
          if (e & 1) lsum1 += p; else lsum0 += p;
        }
        D[2 * g] = pkbf(st[mi][4 * g + 0], st[mi][4 * g + 1]);
        D[2 * g + 1] = pkbf(st[mi][4 * g + 2], st[mi][4 * g + 3]);
      }
#pragma unroll
      for (int tt = 0; tt < 8; tt++) X[tt] = __shfl_xor(D[tt], 32, 64);

#pragma unroll
      for (int kk = 0; kk < 2; kk++) {
        int kc = 2 * mi + kk;
        int b = 4 * kk;
        unsigned f0 = hi ? X[b + 2] : D[b + 0];
        unsigned f1 = hi ? X[b + 3] : D[b + 1];
        unsigned f2 = hi ? D[b + 2] : X[b + 0];
        unsigned f3 = hi ? D[b + 3] : X[b + 1];
        union { uint4 u; bf16x8 v; } cv;
        cv.u = make_uint4(f0, f1, f2, f3);
        bf16x8 pf = cv.v;
#pragma unroll
        for (int md = 0; md < 2; md++) {
          bf16x8 vf = *(const bf16x8*)&Vs[md * 32 + l31][kc * 16 + hi * 8];
          O[md] = MFMA32(vf, pf, O[md]);
        }
      }
    }
  }

  float l_run = lsum0 + lsum1;
  l_run += __shfl_xor(l_run, 32, 64);
  float inv = 1.0f / l_run;
  bf16* cp = ctx + ((size_t)n * 2048 + q) * 512 + h * 64;
#pragma unroll
  for (int md = 0; md < 2; md++)
#pragma unroll
    for (int g = 0; g < 4; g++) {
      bf16x4 o4;
#pragma unroll
      for (int e = 0; e < 4; e++) o4[e] = (bf16)(O[md][4 * g + e] * inv);
      *(bf16x4*)(cp + md * 32 + 8 * g + hi * 4) = o4;
    }
}

// ---------------------------------------------------------------------------
// oproj: out = ctx @ wo + hidden (residual), fp32 out. glds staging.
// ---------------------------------------------------------------------------
__global__ __launch_bounds__(256) void oproj_gemm(
    const bf16* __restrict__ ctx, const bf16* __restrict__ wt_o,
    const float* __restrict__ hidden, float* __restrict__ out) {
  __shared__ __align__(16) char smem[16384];
  bf16* As = (bf16*)smem;
  bf16* Bs = (bf16*)(smem + 8192);
  int t = threadIdx.x;
  int wave = t >> 6, lane = t & 63;
  int quad = lane >> 4, lc = lane & 15;
  int wm = wave >> 1, wn = wave & 1;
  int m0 = blockIdx.x * 128, n0 = blockIdx.y * 128;

  f32x4 acc[4][4];
#pragma unroll
  for (int i = 0; i < 4; i++)
#pragma unroll
    for (int j = 0; j < 4; j++) acc[i][j] = (f32x4){0.f, 0.f, 0.f, 0.f};

  int rw = lane >> 2;
  int c8 = (lane & 3) * 8;
  const bf16* gA = ctx + (size_t)(m0 + wave * 32 + rw) * 512 + c8;
  const bf16* gB = wt_o + (size_t)(n0 + wave * 32 + rw) * 512 + c8;
  bf16* lA = As + wave * 1024;
  bf16* lB = Bs + wave * 1024;

  for (int kt = 0; kt < 16; ++kt) {
    int k0 = kt * 32;
    __syncthreads();
    glds16(gA + k0, lA);
    glds16(gA + 16 * 512 + k0, lA + 512);
    glds16(gB + k0, lB);
    glds16(gB + 16 * 512 + k0, lB + 512);
    __syncthreads();
    bf16x8 af[4], bfr[4];
#pragma unroll
    for (int i = 0; i < 4; i++)
      af[i] = *(const bf16x8*)&As[(wm * 64 + i * 16 + lc) * 32 + quad * 8];
#pragma unroll
    for (int j = 0; j < 4; j++)
      bfr[j] = *(const bf16x8*)&Bs[(wn * 64 + j * 16 + lc) * 32 + quad * 8];
#pragma unroll
    for (int i = 0; i < 4; i++)
#pragma unroll
      for (int j = 0; j < 4; j++)
        acc[i][j] = MFMA16(af[i], bfr[j], acc[i][j]);
  }

#pragma unroll
  for (int i = 0; i < 4; i++) {
#pragma unroll
    for (int j = 0; j < 4; j++) {
#pragma unroll
      for (int r = 0; r < 4; r++) {
        int grow = m0 + wm * 64 + i * 16 + quad * 4 + r;
        int gcol = n0 + wn * 64 + j * 16 + lc;
        size_t idx = (size_t)grow * 512 + gcol;
        out[idx] = acc[i][j][r] + hidden[idx];
      }
    }
  }
}

// ---------------------------------------------------------------------------
extern "C" void kernel_launch(void* const* d_in, const int* in_sizes, int n_in,
                              void* d_out, int out_size, void* d_ws, size_t ws_size,
                              hipStream_t stream) {
  const float* hidden = (const float*)d_in[0];
  const float* ln_w = (const float*)d_in[1];
  const float* wq = (const float*)d_in[2];
  const float* wk = (const float*)d_in[3];
  const float* wv = (const float*)d_in[4];
  const float* wo = (const float*)d_in[5];
  const float* table = (const float*)d_in[6];

  float* out_hidden = (float*)d_out;                       // 8*2048*512
  float* out_bias = out_hidden + (size_t)8 * 2048 * 512;   // 8*2048*2048
  float* out_remain = out_bias + (size_t)8 * 2048 * 2048;  // 8

  char* ws = (char*)d_ws;
  bf16* normed = (bf16*)(ws + 0);            // 16 MiB (reused as ctx later)
  float* lut = (float*)(ws + 16777216);      // 128 KiB
  float4* lutq = (float4*)(ws + 16908288);   // 512 KiB
  bf16* wt_qkv = (bf16*)(ws + 17432576);     // 1.5 MiB
  bf16* wt_o = (bf16*)(ws + 19005440);       // 0.5 MiB
  bf16* qb = (bf16*)(ws + 19529728);         // 16 MiB each
  bf16* kb = qb + (size_t)8 * 8 * 2048 * 64;
  bf16* vtb = kb + (size_t)8 * 8 * 2048 * 64;
  bf16* ctx = normed;  // alias: normed consumed by qkv before attn writes ctx

  prep_kernel<<<dim3(5376), dim3(256), 0, stream>>>(
      hidden, ln_w, wq, wk, wv, wo, table, normed, lut, lutq, out_remain,
      wt_qkv, wt_o);
  qkv_gemm<<<dim3(128, 12), dim3(256), 0, stream>>>(normed, wt_qkv, qb, kb, vtb);
  attn_bias_kernel<<<dim3(1024 + 32768), dim3(256), 0, stream>>>(
      qb, kb, vtb, lutq, lut, ctx, out_bias);
  oproj_gemm<<<dim3(128, 4), dim3(256), 0, stream>>>(ctx, wt_o, hidden, out_hidden);
}